// Round 9
// baseline (166.817 us; speedup 1.0000x reference)
//
#include <hip/hip_runtime.h>
#include <hip/hip_bf16.h>
#include <math.h>

// Bidirectional cross-attention (B=8, L=2048, D=128, fp32 in/out).
// v9: 16-wave blocks (4 waves/SIMD). Wave (wv,wq) owns i32 rows x j32 quarter
// of a 128x128 tile; single-pass fp16 E (X read from L2 per tile); in-register
// softmax; P->A relayout via cvt_pkrtz + shfl_xor(32); 4-way flash merge in
// the retired LDS pool. One barrier per j-tile (16 total).

#define LSEQ 2048
#define DIM  128
#define NBATCH 8
#define BM 128
#define BJ 128
#define NJT (LSEQ / BJ)   // 16
#define THR_DEFER 8.0f
#define PLANE (NBATCH * LSEQ * DIM)   // 2097152 elems (4 MiB as fp16)

typedef _Float16 halfT;
typedef halfT v8h  __attribute__((ext_vector_type(8)));
typedef float v16f __attribute__((ext_vector_type(16)));
typedef float v4f  __attribute__((ext_vector_type(4)));
typedef unsigned v4u __attribute__((ext_vector_type(4)));

__device__ __forceinline__ unsigned pk2u(float a, float b) {
    auto p = __builtin_amdgcn_cvt_pkrtz(a, b);   // __fp16 ext_vector(2)
    return __builtin_bit_cast(unsigned, p);
}

__device__ __forceinline__ void gload16(const void* g, void* l) {
    __builtin_amdgcn_global_load_lds(
        (const __attribute__((address_space(1))) unsigned int*)g,
        (__attribute__((address_space(3))) unsigned int*)l, 16, 0, 0);
}

__device__ __forceinline__ v16f vz16() {
    v16f z;
    #pragma unroll
    for (int r = 0; r < 16; ++r) z[r] = 0.f;
    return z;
}

// ---------------- prepass: fp32 -> {hi, tr-hi} fp16 planes ----------------
__global__ __launch_bounds__(256, 4)
void prepass_kernel(const float* __restrict__ S1, const float* __restrict__ S2,
                    short* __restrict__ ws)
{
    __shared__ short Th[DIM][66];   // transposed hi tile [d][r]
    const int lt = blockIdx.x;      // l-tile (64 rows)
    const int bb = blockIdx.y;
    const int tn = blockIdx.z;      // tensor 0=S1, 1=S2
    const float* src = (tn ? S2 : S1) + ((size_t)bb * LSEQ + (size_t)lt * 64) * DIM;
    short* hi = ws + (size_t)tn * 2 * PLANE + ((size_t)bb * LSEQ + (size_t)lt * 64) * DIM;
    short* tr = ws + (size_t)tn * 2 * PLANE + (size_t)PLANE
              + (size_t)bb * DIM * LSEQ + (size_t)lt * 64;
    const int tid = threadIdx.x;
    #pragma unroll
    for (int it = 0; it < 8; ++it) {
        int idx = tid + it * 256;       // 2048 float4 = 64x128 floats
        int r = idx >> 5;               // 0..63
        int c = (idx & 31) * 4;         // 0..124
        float4 v = *(const float4*)(src + (size_t)r * DIM + c);
        halfT h0 = (halfT)v.x, h1 = (halfT)v.y, h2 = (halfT)v.z, h3 = (halfT)v.w;
        short b0 = __builtin_bit_cast(short, h0), b1 = __builtin_bit_cast(short, h1);
        short b2 = __builtin_bit_cast(short, h2), b3 = __builtin_bit_cast(short, h3);
        *(short4*)&hi[(size_t)r * DIM + c] = make_short4(b0, b1, b2, b3);
        Th[c + 0][r] = b0; Th[c + 1][r] = b1;
        Th[c + 2][r] = b2; Th[c + 3][r] = b3;
    }
    __syncthreads();
    #pragma unroll
    for (int it = 0; it < 16; ++it) {
        int idx = tid + it * 256;       // 128x32 ints
        int d = idx >> 5;
        int c = (idx & 31) * 2;
        unsigned val = (unsigned)(unsigned short)Th[d][c]
                     | ((unsigned)(unsigned short)Th[d][c + 1] << 16);
        *(unsigned*)(tr + (size_t)d * LSEQ + c) = val;
    }
}

// ---------------- main flash kernel ----------------
__global__ __launch_bounds__(1024, 4)
void xattn_main(const short* __restrict__ ws, float* __restrict__ out)
{
    // pool: loop = Y dbuf (2x32KB @0) + Vt dbuf (2x32KB @65536);
    // epilogue = OBa (64KB @0) + OBb (64KB @65536), both [d128][i128] fp32.
    __shared__ char pool[131072];
    __shared__ float facL[16][32];           // in-loop defer-rescale factors
    __shared__ float mEx[4][4][32], sEx[4][4][32], facM[4][4][32];

    const int tid  = threadIdx.x;
    const int lane = tid & 63;
    const int wave = tid >> 6;      // 0..15
    const int wv   = wave & 3;      // i-group: rows wv*32..+31
    const int wq   = wave >> 2;     // j-quarter: j wq*32..+31 of each tile
    const int li   = lane & 31;
    const int h    = lane >> 5;     // k-half
    const int swz  = (li & 15) << 4;

    // XCD-grouped decode: 16 blocks sharing one (side,batch) Y-stream per XCD.
    const int bx   = blockIdx.x;
    const int xcd  = bx & 7;
    const int slot = bx >> 3;               // 0..31
    const int g    = xcd * 2 + (slot >> 4); // 0..15
    const int rt   = slot & 15;
    const int side = g >> 3;
    const int bb   = g & 7;

    const short* XHg = ws + (size_t)side * 2 * PLANE + ((size_t)bb * LSEQ + (size_t)rt * BM) * DIM;
    const short* YHg = ws + (size_t)(side ^ 1) * 2 * PLANE + (size_t)bb * LSEQ * DIM;
    const short* YTg = ws + (size_t)(side ^ 1) * 2 * PLANE + (size_t)PLANE + (size_t)bb * DIM * LSEQ;
    float* O = out + (size_t)side * PLANE + ((size_t)bb * LSEQ + (size_t)rt * BM) * DIM;

    const size_t xoff = ((size_t)(wv * 32 + li)) * DIM + h * 8;   // X row base

    float runm = -INFINITY, runs = 0.f;

    // staging: 4 gload16 per wave per tile (32 Y chunks + 32 Vt chunks / 16 waves)
    auto STAGE = [&](int jt, int b) {
        #pragma unroll
        for (int k = 0; k < 2; ++k) {
            const int c   = wave * 2 + k;          // Y chunk: 4 rows x 256B
            const int row = c * 4 + (lane >> 4);
            const int cb  = ((lane & 15) * 16) ^ ((row & 15) << 4);
            gload16((const char*)YHg + ((size_t)(jt * BJ + row)) * 256 + cb,
                    pool + b * 32768 + c * 1024);
        }
        #pragma unroll
        for (int k = 0; k < 2; ++k) {
            const int c = wave * 2 + k;            // Vt chunk: 4 d-rows x 256B
            const int d = c * 4 + (lane >> 4);
            const int cb = ((lane & 15) * 16) ^ ((d & 15) << 4);
            gload16((const char*)YTg + (size_t)d * (LSEQ * 2) + (size_t)jt * (BJ * 2) + cb,
                    pool + 65536 + b * 32768 + c * 1024);
        }
    };

    v16f o0 = vz16(), o1 = vz16(), o2 = vz16(), o3 = vz16();

    STAGE(0, 0);
    __syncthreads();    // prologue: full drain once

    for (int jt = 0; jt < NJT; ++jt) {
        const int cur = jt & 1;
        if (jt + 1 < NJT) STAGE(jt + 1, cur ^ 1);   // fly during compute
        const char* Yc = (const char*)pool + cur * 32768;
        const char* Vc = (const char*)pool + 65536 + cur * 32768;

        // ---- E^T slice: this wave's j32 x i32, K=128, single fp16 pass ----
        v16f e = vz16();
        const int yrow = wq * 32 + li;
        __builtin_amdgcn_s_setprio(1);
        #pragma unroll
        for (int ks = 0; ks < 8; ++ks) {
            const int cb = (ks * 32 + h * 16) ^ swz;
            v8h ya = *(const v8h*)(Yc + yrow * 256 + cb);
            v8h xv = *(const v8h*)(const void*)(XHg + xoff + ks * 16);
            e = __builtin_amdgcn_mfma_f32_32x32x16_f16(ya, xv, e, 0, 0, 0);
        }
        __builtin_amdgcn_s_setprio(0);

        // ---- row stats (lane owns row i = wv*32+li; fold k-halves) ----
        float a0 = fmaxf(e[0], e[1]),  a1 = fmaxf(e[2], e[3]);
        float a2 = fmaxf(e[4], e[5]),  a3 = fmaxf(e[6], e[7]);
        float a4 = fmaxf(e[8], e[9]),  a5 = fmaxf(e[10], e[11]);
        float a6 = fmaxf(e[12], e[13]), a7 = fmaxf(e[14], e[15]);
        float mt = fmaxf(fmaxf(fmaxf(a0, a1), fmaxf(a2, a3)),
                         fmaxf(fmaxf(a4, a5), fmaxf(a6, a7)));
        mt = fmaxf(mt, __shfl_xor(mt, 32));

        float f = 1.0f;
        if (mt > runm + THR_DEFER) { f = __expf(runm - mt); runm = mt; runs *= f; }
        if (lane < 32) facL[wave][lane] = f;
        const bool anyr = __any(f != 1.0f);

        // ---- P = exp(E - m) in-register; sum ----
        float s = 0.f;
        #pragma unroll
        for (int r = 0; r < 16; ++r) { e[r] = __expf(e[r] - runm); s += e[r]; }
        s += __shfl_xor(s, 32);
        runs += s;

        // ---- acc rescale (rare: defer-max) ----
        if (anyr) {
            #pragma unroll
            for (int r = 0; r < 16; ++r) {
                const float fr = facL[wave][(r & 3) + 8 * (r >> 2) + 4 * h];
                o0[r] *= fr; o1[r] *= fr; o2[r] *= fr; o3[r] *= fr;
            }
        }

        // ---- PV over this wave's j32: P via D->A half-swap ----
        __builtin_amdgcn_s_setprio(1);
        #pragma unroll
        for (int ks2 = 0; ks2 < 2; ++ks2) {
            const int base = ks2 * 8;
            unsigned kA0 = pk2u(e[base + 0], e[base + 1]);
            unsigned kA1 = pk2u(e[base + 2], e[base + 3]);
            unsigned kB0 = pk2u(e[base + 4], e[base + 5]);
            unsigned kB1 = pk2u(e[base + 6], e[base + 7]);
            unsigned r0 = (unsigned)__shfl_xor((int)(h ? kA0 : kB0), 32);
            unsigned r1 = (unsigned)__shfl_xor((int)(h ? kA1 : kB1), 32);
            v4u U;
            U[0] = h ? r0 : kA0;
            U[1] = h ? r1 : kA1;
            U[2] = h ? kB0 : r0;
            U[3] = h ? kB1 : r1;
            v8h pa = __builtin_bit_cast(v8h, U);
            const int cj = wq * 64 + ks2 * 32 + h * 16;
            v8h vb0 = *(const v8h*)(Vc + (0 * 32 + li) * 256 + (cj ^ swz));
            v8h vb1 = *(const v8h*)(Vc + (1 * 32 + li) * 256 + (cj ^ swz));
            v8h vb2 = *(const v8h*)(Vc + (2 * 32 + li) * 256 + (cj ^ swz));
            v8h vb3 = *(const v8h*)(Vc + (3 * 32 + li) * 256 + (cj ^ swz));
            o0 = __builtin_amdgcn_mfma_f32_32x32x16_f16(pa, vb0, o0, 0, 0, 0);
            o1 = __builtin_amdgcn_mfma_f32_32x32x16_f16(pa, vb1, o1, 0, 0, 0);
            o2 = __builtin_amdgcn_mfma_f32_32x32x16_f16(pa, vb2, o2, 0, 0, 0);
            o3 = __builtin_amdgcn_mfma_f32_32x32x16_f16(pa, vb3, o3, 0, 0, 0);
        }
        __builtin_amdgcn_s_setprio(0);

        asm volatile("s_waitcnt vmcnt(0) lgkmcnt(0)" ::: "memory");
        __builtin_amdgcn_s_barrier();
        __builtin_amdgcn_sched_barrier(0);
    }

    // ================= epilogue: 4-way flash merge over j-quarters =========
    if (lane < 32) { mEx[wv][wq][lane] = runm; sEx[wv][wq][lane] = runs; }
    __syncthreads();
    if (tid < 128) {
        const int wv2 = tid >> 5, li2 = tid & 31;
        float m0 = mEx[wv2][0][li2], m1 = mEx[wv2][1][li2];
        float m2 = mEx[wv2][2][li2], m3 = mEx[wv2][3][li2];
        float mM = fmaxf(fmaxf(m0, m1), fmaxf(m2, m3));
        float e0 = __expf(m0 - mM), e1 = __expf(m1 - mM);
        float e2 = __expf(m2 - mM), e3 = __expf(m3 - mM);
        float inv = 1.0f / (sEx[wv2][0][li2] * e0 + sEx[wv2][1][li2] * e1 +
                            sEx[wv2][2][li2] * e2 + sEx[wv2][3][li2] * e3);
        facM[wv2][0][li2] = e0 * inv;
        facM[wv2][1][li2] = e1 * inv;
        facM[wv2][2][li2] = e2 * inv;
        facM[wv2][3][li2] = e3 * inv;
    }
    __syncthreads();
    // scale own partial by merge factor
    #pragma unroll
    for (int r = 0; r < 16; ++r) {
        const float fr = facM[wv][wq][(r & 3) + 8 * (r >> 2) + 4 * h];
        o0[r] *= fr; o1[r] *= fr; o2[r] *= fr; o3[r] *= fr;
    }

    // OBt[d][i] fp32, 16B-chunk XOR swizzle by li
    auto obWrite = [&](char* basep) {
        #pragma unroll
        for (int rg = 0; rg < 4; ++rg) {
            const int chs = ((wv * 8 + rg * 2 + h) ^ li) << 4;
            *(v4f*)(basep + (0 * 32 + li) * 512 + chs) =
                (v4f){o0[rg * 4 + 0], o0[rg * 4 + 1], o0[rg * 4 + 2], o0[rg * 4 + 3]};
            *(v4f*)(basep + (1 * 32 + li) * 512 + chs) =
                (v4f){o1[rg * 4 + 0], o1[rg * 4 + 1], o1[rg * 4 + 2], o1[rg * 4 + 3]};
            *(v4f*)(basep + (2 * 32 + li) * 512 + chs) =
                (v4f){o2[rg * 4 + 0], o2[rg * 4 + 1], o2[rg * 4 + 2], o2[rg * 4 + 3]};
            *(v4f*)(basep + (3 * 32 + li) * 512 + chs) =
                (v4f){o3[rg * 4 + 0], o3[rg * 4 + 1], o3[rg * 4 + 2], o3[rg * 4 + 3]};
        }
    };
    auto obAdd = [&](const char* basep) {
        #pragma unroll
        for (int rg = 0; rg < 4; ++rg) {
            const int chs = ((wv * 8 + rg * 2 + h) ^ li) << 4;
            v4f v0 = *(const v4f*)(basep + (0 * 32 + li) * 512 + chs);
            v4f v1 = *(const v4f*)(basep + (1 * 32 + li) * 512 + chs);
            v4f v2 = *(const v4f*)(basep + (2 * 32 + li) * 512 + chs);
            v4f v3 = *(const v4f*)(basep + (3 * 32 + li) * 512 + chs);
            #pragma unroll
            for (int q = 0; q < 4; ++q) {
                o0[rg * 4 + q] += v0[q];
                o1[rg * 4 + q] += v1[q];
                o2[rg * 4 + q] += v2[q];
                o3[rg * 4 + q] += v3[q];
            }
        }
    };

    __syncthreads();   // pool free for reuse
    if (wq == 1) obWrite(pool);
    if (wq == 3) obWrite(pool + 65536);
    __syncthreads();
    if (wq == 0) obAdd(pool);
    if (wq == 2) obAdd(pool + 65536);
    __syncthreads();
    if (wq == 2) obWrite(pool);
    __syncthreads();
    if (wq == 0) {
        obAdd(pool);
        #pragma unroll
        for (int r = 0; r < 16; ++r) {
            const int i = wv * 32 + (r & 3) + 8 * (r >> 2) + 4 * h;
            float* orow = O + (size_t)i * DIM;
            orow[0 * 32 + li] = o0[r];
            orow[1 * 32 + li] = o1[r];
            orow[2 * 32 + li] = o2[r];
            orow[3 * 32 + li] = o3[r];
        }
    }
}

extern "C" void kernel_launch(void* const* d_in, const int* in_sizes, int n_in,
                              void* d_out, int out_size, void* d_ws, size_t ws_size,
                              hipStream_t stream) {
    const float* s1 = (const float*)d_in[0];
    const float* s2 = (const float*)d_in[1];
    float* out = (float*)d_out;
    short* ws = (short*)d_ws;   // 4 * PLANE * 2B = 16 MiB
    prepass_kernel<<<dim3(LSEQ / 64, NBATCH, 2), 256, 0, stream>>>(s1, s2, ws);
    xattn_main<<<dim3(256), 1024, 0, stream>>>(ws, out);
}

// Round 10
// 71.147 us; speedup vs baseline: 2.3447x; 2.3447x over previous
//
#include <hip/hip_runtime.h>
#include <hip/hip_bf16.h>
#include <math.h>

// Bidirectional cross-attention (B=8, L=2048, D=128, fp32 in/out).
// v10: 16-wave blocks (4 waves/SIMD), spill-proof. Wave (wv,wq) owns i32 x j32
// of a 128x128 tile. Single-pass fp16 E; X staged in LDS (not regs); Y single-
// buffered, Vt double-buffered; 2 barriers/tile; in-register softmax with
// shfl-broadcast rescale; 4-way flash merge in retired LDS pool.

#define LSEQ 2048
#define DIM  128
#define NBATCH 8
#define BM 128
#define BJ 128
#define NJT (LSEQ / BJ)   // 16
#define THR_DEFER 8.0f
#define PLANE (NBATCH * LSEQ * DIM)   // 2097152 elems (4 MiB as fp16)

typedef _Float16 halfT;
typedef halfT v8h  __attribute__((ext_vector_type(8)));
typedef float v16f __attribute__((ext_vector_type(16)));
typedef float v4f  __attribute__((ext_vector_type(4)));
typedef unsigned v4u __attribute__((ext_vector_type(4)));

__device__ __forceinline__ unsigned pk2u(float a, float b) {
    auto p = __builtin_amdgcn_cvt_pkrtz(a, b);   // __fp16 ext_vector(2)
    return __builtin_bit_cast(unsigned, p);
}

__device__ __forceinline__ void gload16(const void* g, void* l) {
    __builtin_amdgcn_global_load_lds(
        (const __attribute__((address_space(1))) unsigned int*)g,
        (__attribute__((address_space(3))) unsigned int*)l, 16, 0, 0);
}

__device__ __forceinline__ v16f vz16() {
    v16f z;
    #pragma unroll
    for (int r = 0; r < 16; ++r) z[r] = 0.f;
    return z;
}

// ---------------- prepass: fp32 -> {hi, tr-hi} fp16 planes ----------------
__global__ __launch_bounds__(256, 4)
void prepass_kernel(const float* __restrict__ S1, const float* __restrict__ S2,
                    short* __restrict__ ws)
{
    __shared__ short Th[DIM][66];   // transposed hi tile [d][r]
    const int lt = blockIdx.x;      // l-tile (64 rows)
    const int bb = blockIdx.y;
    const int tn = blockIdx.z;      // tensor 0=S1, 1=S2
    const float* src = (tn ? S2 : S1) + ((size_t)bb * LSEQ + (size_t)lt * 64) * DIM;
    short* hi = ws + (size_t)tn * 2 * PLANE + ((size_t)bb * LSEQ + (size_t)lt * 64) * DIM;
    short* tr = ws + (size_t)tn * 2 * PLANE + (size_t)PLANE
              + (size_t)bb * DIM * LSEQ + (size_t)lt * 64;
    const int tid = threadIdx.x;
    #pragma unroll
    for (int it = 0; it < 8; ++it) {
        int idx = tid + it * 256;       // 2048 float4 = 64x128 floats
        int r = idx >> 5;               // 0..63
        int c = (idx & 31) * 4;         // 0..124
        float4 v = *(const float4*)(src + (size_t)r * DIM + c);
        halfT h0 = (halfT)v.x, h1 = (halfT)v.y, h2 = (halfT)v.z, h3 = (halfT)v.w;
        short b0 = __builtin_bit_cast(short, h0), b1 = __builtin_bit_cast(short, h1);
        short b2 = __builtin_bit_cast(short, h2), b3 = __builtin_bit_cast(short, h3);
        *(short4*)&hi[(size_t)r * DIM + c] = make_short4(b0, b1, b2, b3);
        Th[c + 0][r] = b0; Th[c + 1][r] = b1;
        Th[c + 2][r] = b2; Th[c + 3][r] = b3;
    }
    __syncthreads();
    #pragma unroll
    for (int it = 0; it < 16; ++it) {
        int idx = tid + it * 256;       // 128x32 ints
        int d = idx >> 5;
        int c = (idx & 31) * 2;
        unsigned val = (unsigned)(unsigned short)Th[d][c]
                     | ((unsigned)(unsigned short)Th[d][c + 1] << 16);
        *(unsigned*)(tr + (size_t)d * LSEQ + c) = val;
    }
}

// ---------------- main flash kernel ----------------
__global__ __launch_bounds__(1024, 1)
void xattn_main(const short* __restrict__ ws, float* __restrict__ out)
{
    // pool layout (loop):  [0,32K) Y tile (single buf, [128j][256B] swz)
    //                      [32K,96K) Vt dbuf ([128d][256B] swz)
    //                      [96K,128K) X tile ([128i][256B] swz, static)
    // epilogue reuse:      OBa = [0,64K), OBb = [64K,128K), both [128d][128i] f32
    __shared__ char pool[131072];
    __shared__ float mEx[4][4][32], sEx[4][4][32], facM[4][4][32];

    const int tid  = threadIdx.x;
    const int lane = tid & 63;
    const int wave = tid >> 6;      // 0..15
    const int wv   = wave & 3;      // i-group: rows wv*32..+31
    const int wq   = wave >> 2;     // j-quarter: j wq*32..+31 of each tile
    const int li   = lane & 31;
    const int h    = lane >> 5;     // k-half
    const int swz  = (li & 15) << 4;

    // XCD-grouped decode: 16 blocks sharing one (side,batch) Y-stream per XCD.
    const int bx   = blockIdx.x;
    const int xcd  = bx & 7;
    const int slot = bx >> 3;               // 0..31
    const int g    = xcd * 2 + (slot >> 4); // 0..15
    const int rt   = slot & 15;
    const int side = g >> 3;
    const int bb   = g & 7;

    const short* XHg = ws + (size_t)side * 2 * PLANE + ((size_t)bb * LSEQ + (size_t)rt * BM) * DIM;
    const short* YHg = ws + (size_t)(side ^ 1) * 2 * PLANE + (size_t)bb * LSEQ * DIM;
    const short* YTg = ws + (size_t)(side ^ 1) * 2 * PLANE + (size_t)PLANE + (size_t)bb * DIM * LSEQ;
    float* O = out + (size_t)side * PLANE + ((size_t)bb * LSEQ + (size_t)rt * BM) * DIM;

    float runm = -INFINITY, runs = 0.f;

    // staging: each wave owns 2 Y chunks + 2 Vt chunks (1KB each) per tile.
    const int ch0 = wave * 2;
    const int sr0 = ch0 * 4 + (lane >> 4);          // Y/X row for chunk 0
    const int sr1 = (ch0 + 1) * 4 + (lane >> 4);    // row for chunk 1
    const int sc0 = ((lane & 15) * 16) ^ ((sr0 & 15) << 4);
    const int sc1 = ((lane & 15) * 16) ^ ((sr1 & 15) << 4);

    auto STAGE_Y = [&](int jt) {
        gload16((const char*)YHg + ((size_t)(jt * BJ + sr0)) * 256 + sc0,
                pool + ch0 * 1024);
        gload16((const char*)YHg + ((size_t)(jt * BJ + sr1)) * 256 + sc1,
                pool + (ch0 + 1) * 1024);
    };
    auto STAGE_V = [&](int jt, int b) {
        gload16((const char*)YTg + (size_t)sr0 * (LSEQ * 2) + (size_t)jt * (BJ * 2) + sc0,
                pool + 32768 + b * 32768 + ch0 * 1024);
        gload16((const char*)YTg + (size_t)sr1 * (LSEQ * 2) + (size_t)jt * (BJ * 2) + sc1,
                pool + 32768 + b * 32768 + (ch0 + 1) * 1024);
    };

    v16f o0 = vz16(), o1 = vz16(), o2 = vz16(), o3 = vz16();

    // prologue: X (static), Y[0], Vt[0]
    gload16((const char*)XHg + (size_t)sr0 * 256 + sc0, pool + 98304 + ch0 * 1024);
    gload16((const char*)XHg + (size_t)sr1 * 256 + sc1, pool + 98304 + (ch0 + 1) * 1024);
    STAGE_Y(0);
    STAGE_V(0, 0);
    asm volatile("s_waitcnt vmcnt(0)" ::: "memory");
    __syncthreads();

    const int yrow = wq * 32 + li;
    const int xrow = wv * 32 + li;

    for (int jt = 0; jt < NJT; ++jt) {
        const int cur = jt & 1;

        // ---- E^T slice: this wave's j32 x i32, K=128, single fp16 pass ----
        v16f e = vz16();
        __builtin_amdgcn_s_setprio(1);
        #pragma unroll
        for (int ks = 0; ks < 8; ++ks) {
            const int cb = ks * 32 + h * 16;
            v8h ya = *(const v8h*)(pool + yrow * 256 + (cb ^ ((yrow & 15) << 4)));
            v8h xv = *(const v8h*)(pool + 98304 + xrow * 256 + (cb ^ ((xrow & 15) << 4)));
            e = __builtin_amdgcn_mfma_f32_32x32x16_f16(ya, xv, e, 0, 0, 0);
        }
        __builtin_amdgcn_s_setprio(0);

        asm volatile("s_waitcnt lgkmcnt(0)" ::: "memory");
        __builtin_amdgcn_s_barrier();           // B1: all E reads of Y done
        __builtin_amdgcn_sched_barrier(0);

        // ---- issue next tile's stages (fly under softmax + PV) ----
        if (jt + 1 < NJT) {
            STAGE_Y(jt + 1);
            STAGE_V(jt + 1, cur ^ 1);
        }

        // ---- row stats (lane owns row i = wv*32+li; fold k-halves) ----
        float a0 = fmaxf(e[0], e[1]),  a1 = fmaxf(e[2], e[3]);
        float a2 = fmaxf(e[4], e[5]),  a3 = fmaxf(e[6], e[7]);
        float a4 = fmaxf(e[8], e[9]),  a5 = fmaxf(e[10], e[11]);
        float a6 = fmaxf(e[12], e[13]), a7 = fmaxf(e[14], e[15]);
        float mt = fmaxf(fmaxf(fmaxf(a0, a1), fmaxf(a2, a3)),
                         fmaxf(fmaxf(a4, a5), fmaxf(a6, a7)));
        mt = fmaxf(mt, __shfl_xor(mt, 32));

        float f = 1.0f;
        if (mt > runm + THR_DEFER) { f = __expf(runm - mt); runm = mt; runs *= f; }

        // ---- P = exp(E - m) in-register; sum ----
        float s = 0.f;
        #pragma unroll
        for (int r = 0; r < 16; ++r) { e[r] = __expf(e[r] - runm); s += e[r]; }
        s += __shfl_xor(s, 32);
        runs += s;

        // ---- acc rescale (rare: defer-max); factors via shfl broadcast ----
        if (__any(f != 1.0f)) {
            #pragma unroll
            for (int r = 0; r < 16; ++r) {
                const float fr = __shfl(f, (r & 3) + 8 * (r >> 2) + 4 * h);
                o0[r] *= fr; o1[r] *= fr; o2[r] *= fr; o3[r] *= fr;
            }
        }

        // ---- PV over this wave's j32: P via D->A half-swap ----
        const char* Vc = pool + 32768 + cur * 32768;
        __builtin_amdgcn_s_setprio(1);
        #pragma unroll
        for (int ks2 = 0; ks2 < 2; ++ks2) {
            const int base = ks2 * 8;
            unsigned kA0 = pk2u(e[base + 0], e[base + 1]);
            unsigned kA1 = pk2u(e[base + 2], e[base + 3]);
            unsigned kB0 = pk2u(e[base + 4], e[base + 5]);
            unsigned kB1 = pk2u(e[base + 6], e[base + 7]);
            unsigned r0 = (unsigned)__shfl_xor((int)(h ? kA0 : kB0), 32);
            unsigned r1 = (unsigned)__shfl_xor((int)(h ? kA1 : kB1), 32);
            v4u U;
            U[0] = h ? r0 : kA0;
            U[1] = h ? r1 : kA1;
            U[2] = h ? kB0 : r0;
            U[3] = h ? kB1 : r1;
            v8h pa = __builtin_bit_cast(v8h, U);
            const int cj = wq * 64 + ks2 * 32 + h * 16;
            v8h vb0 = *(const v8h*)(Vc + (0 * 32 + li) * 256 + (cj ^ ((li & 15) << 4)));
            v8h vb1 = *(const v8h*)(Vc + (1 * 32 + li) * 256 + (cj ^ ((li & 15) << 4)));
            v8h vb2 = *(const v8h*)(Vc + (2 * 32 + li) * 256 + (cj ^ ((li & 15) << 4)));
            v8h vb3 = *(const v8h*)(Vc + (3 * 32 + li) * 256 + (cj ^ ((li & 15) << 4)));
            o0 = __builtin_amdgcn_mfma_f32_32x32x16_f16(pa, vb0, o0, 0, 0, 0);
            o1 = __builtin_amdgcn_mfma_f32_32x32x16_f16(pa, vb1, o1, 0, 0, 0);
            o2 = __builtin_amdgcn_mfma_f32_32x32x16_f16(pa, vb2, o2, 0, 0, 0);
            o3 = __builtin_amdgcn_mfma_f32_32x32x16_f16(pa, vb3, o3, 0, 0, 0);
        }
        __builtin_amdgcn_s_setprio(0);

        asm volatile("s_waitcnt vmcnt(0) lgkmcnt(0)" ::: "memory");
        __builtin_amdgcn_s_barrier();           // B2: stages landed, PV done
        __builtin_amdgcn_sched_barrier(0);
    }

    // ================= epilogue: 4-way flash merge over j-quarters =========
    if (lane < 32) { mEx[wv][wq][lane] = runm; sEx[wv][wq][lane] = runs; }
    __syncthreads();
    if (tid < 128) {
        const int wv2 = tid >> 5, li2 = tid & 31;
        float m0 = mEx[wv2][0][li2], m1 = mEx[wv2][1][li2];
        float m2 = mEx[wv2][2][li2], m3 = mEx[wv2][3][li2];
        float mM = fmaxf(fmaxf(m0, m1), fmaxf(m2, m3));
        float e0 = __expf(m0 - mM), e1 = __expf(m1 - mM);
        float e2 = __expf(m2 - mM), e3 = __expf(m3 - mM);
        float inv = 1.0f / (sEx[wv2][0][li2] * e0 + sEx[wv2][1][li2] * e1 +
                            sEx[wv2][2][li2] * e2 + sEx[wv2][3][li2] * e3);
        facM[wv2][0][li2] = e0 * inv;
        facM[wv2][1][li2] = e1 * inv;
        facM[wv2][2][li2] = e2 * inv;
        facM[wv2][3][li2] = e3 * inv;
    }
    __syncthreads();
    #pragma unroll
    for (int r = 0; r < 16; ++r) {
        const float fr = facM[wv][wq][(r & 3) + 8 * (r >> 2) + 4 * h];
        o0[r] *= fr; o1[r] *= fr; o2[r] *= fr; o3[r] *= fr;
    }

    // OBt[d][i] fp32, 16B-chunk XOR swizzle by li
    auto obWrite = [&](char* basep) {
        #pragma unroll
        for (int rg = 0; rg < 4; ++rg) {
            const int chs = ((wv * 8 + rg * 2 + h) ^ li) << 4;
            *(v4f*)(basep + (0 * 32 + li) * 512 + chs) =
                (v4f){o0[rg * 4 + 0], o0[rg * 4 + 1], o0[rg * 4 + 2], o0[rg * 4 + 3]};
            *(v4f*)(basep + (1 * 32 + li) * 512 + chs) =
                (v4f){o1[rg * 4 + 0], o1[rg * 4 + 1], o1[rg * 4 + 2], o1[rg * 4 + 3]};
            *(v4f*)(basep + (2 * 32 + li) * 512 + chs) =
                (v4f){o2[rg * 4 + 0], o2[rg * 4 + 1], o2[rg * 4 + 2], o2[rg * 4 + 3]};
            *(v4f*)(basep + (3 * 32 + li) * 512 + chs) =
                (v4f){o3[rg * 4 + 0], o3[rg * 4 + 1], o3[rg * 4 + 2], o3[rg * 4 + 3]};
        }
    };
    auto obAdd = [&](const char* basep) {
        #pragma unroll
        for (int rg = 0; rg < 4; ++rg) {
            const int chs = ((wv * 8 + rg * 2 + h) ^ li) << 4;
            v4f v0 = *(const v4f*)(basep + (0 * 32 + li) * 512 + chs);
            v4f v1 = *(const v4f*)(basep + (1 * 32 + li) * 512 + chs);
            v4f v2 = *(const v4f*)(basep + (2 * 32 + li) * 512 + chs);
            v4f v3 = *(const v4f*)(basep + (3 * 32 + li) * 512 + chs);
            #pragma unroll
            for (int q = 0; q < 4; ++q) {
                o0[rg * 4 + q] += v0[q];
                o1[rg * 4 + q] += v1[q];
                o2[rg * 4 + q] += v2[q];
                o3[rg * 4 + q] += v3[q];
            }
        }
    };

    __syncthreads();   // pool free for reuse
    if (wq == 1) obWrite(pool);
    if (wq == 3) obWrite(pool + 65536);
    __syncthreads();
    if (wq == 0) obAdd(pool);
    if (wq == 2) obAdd(pool + 65536);
    __syncthreads();
    if (wq == 2) obWrite(pool);
    __syncthreads();
    if (wq == 0) {
        obAdd(pool);
        #pragma unroll
        for (int r = 0; r < 16; ++r) {
            const int i = wv * 32 + (r & 3) + 8 * (r >> 2) + 4 * h;
            float* orow = O + (size_t)i * DIM;
            orow[0 * 32 + li] = o0[r];
            orow[1 * 32 + li] = o1[r];
            orow[2 * 32 + li] = o2[r];
            orow[3 * 32 + li] = o3[r];
        }
    }
}

extern "C" void kernel_launch(void* const* d_in, const int* in_sizes, int n_in,
                              void* d_out, int out_size, void* d_ws, size_t ws_size,
                              hipStream_t stream) {
    const float* s1 = (const float*)d_in[0];
    const float* s2 = (const float*)d_in[1];
    float* out = (float*)d_out;
    short* ws = (short*)d_ws;   // 4 * PLANE * 2B = 16 MiB
    prepass_kernel<<<dim3(LSEQ / 64, NBATCH, 2), 256, 0, stream>>>(s1, s2, ws);
    xattn_main<<<dim3(256), 1024, 0, stream>>>(ws, out);
}

// Round 11
// 68.812 us; speedup vs baseline: 2.4242x; 1.0339x over previous
//
#include <hip/hip_runtime.h>
#include <hip/hip_bf16.h>
#include <math.h>

// Bidirectional cross-attention (B=8, L=2048, D=128, fp32 in/out).
// v11: minimum-redundancy flash. 16 waves; wave (wA,wB) owns OUTPUT tile
// (i32 = wA*32, d32 = wB*32), accumulated over all j -> acc = 16 regs, no
// epilogue merge. X in registers. Per tile: E (i32 x j32=wB quarter) ->
// cross-wave max via LDS -> P fp16 -> Pt LDS -> PV over full j128.
// 3 barriers/tile; Y single-buf, Vt double-buf, Pt single-buf.

#define LSEQ 2048
#define DIM  128
#define NBATCH 8
#define BM 128
#define BJ 128
#define NJT (LSEQ / BJ)   // 16
#define THR_DEFER 8.0f
#define PLANE (NBATCH * LSEQ * DIM)   // 2097152 elems (4 MiB as fp16)

typedef _Float16 halfT;
typedef halfT v8h  __attribute__((ext_vector_type(8)));
typedef float v16f __attribute__((ext_vector_type(16)));

__device__ __forceinline__ unsigned pk2u(float a, float b) {
    auto p = __builtin_amdgcn_cvt_pkrtz(a, b);   // __fp16 ext_vector(2)
    return __builtin_bit_cast(unsigned, p);
}

__device__ __forceinline__ void gload16(const void* g, void* l) {
    __builtin_amdgcn_global_load_lds(
        (const __attribute__((address_space(1))) unsigned int*)g,
        (__attribute__((address_space(3))) unsigned int*)l, 16, 0, 0);
}

__device__ __forceinline__ v16f vz16() {
    v16f z;
    #pragma unroll
    for (int r = 0; r < 16; ++r) z[r] = 0.f;
    return z;
}

// ---------------- prepass: fp32 -> {hi, tr-hi} fp16 planes ----------------
__global__ __launch_bounds__(256, 4)
void prepass_kernel(const float* __restrict__ S1, const float* __restrict__ S2,
                    short* __restrict__ ws)
{
    __shared__ short Th[DIM][66];   // transposed hi tile [d][r]
    const int lt = blockIdx.x;      // l-tile (64 rows)
    const int bb = blockIdx.y;
    const int tn = blockIdx.z;      // tensor 0=S1, 1=S2
    const float* src = (tn ? S2 : S1) + ((size_t)bb * LSEQ + (size_t)lt * 64) * DIM;
    short* hi = ws + (size_t)tn * 2 * PLANE + ((size_t)bb * LSEQ + (size_t)lt * 64) * DIM;
    short* tr = ws + (size_t)tn * 2 * PLANE + (size_t)PLANE
              + (size_t)bb * DIM * LSEQ + (size_t)lt * 64;
    const int tid = threadIdx.x;
    #pragma unroll
    for (int it = 0; it < 8; ++it) {
        int idx = tid + it * 256;       // 2048 float4 = 64x128 floats
        int r = idx >> 5;               // 0..63
        int c = (idx & 31) * 4;         // 0..124
        float4 v = *(const float4*)(src + (size_t)r * DIM + c);
        halfT h0 = (halfT)v.x, h1 = (halfT)v.y, h2 = (halfT)v.z, h3 = (halfT)v.w;
        short b0 = __builtin_bit_cast(short, h0), b1 = __builtin_bit_cast(short, h1);
        short b2 = __builtin_bit_cast(short, h2), b3 = __builtin_bit_cast(short, h3);
        *(short4*)&hi[(size_t)r * DIM + c] = make_short4(b0, b1, b2, b3);
        Th[c + 0][r] = b0; Th[c + 1][r] = b1;
        Th[c + 2][r] = b2; Th[c + 3][r] = b3;
    }
    __syncthreads();
    #pragma unroll
    for (int it = 0; it < 16; ++it) {
        int idx = tid + it * 256;       // 128x32 ints
        int d = idx >> 5;
        int c = (idx & 31) * 2;
        unsigned val = (unsigned)(unsigned short)Th[d][c]
                     | ((unsigned)(unsigned short)Th[d][c + 1] << 16);
        *(unsigned*)(tr + (size_t)d * LSEQ + c) = val;
    }
}

// ---------------- main flash kernel ----------------
__global__ __launch_bounds__(1024, 1)
void xattn_main(const short* __restrict__ ws, float* __restrict__ out)
{
    // pool: [0,32K) Y tile [128j][256B swz] (single buf)
    //       [32K,96K) Vt dbuf [2][128d][256B swz]
    //       [96K,128K) Pt [128i][256B swz]
    __shared__ char pool[131072];
    __shared__ float maxp[4][4][32];   // [i-group][j-quarter][row]
    __shared__ float sEx[4][4][32];

    const int tid  = threadIdx.x;
    const int lane = tid & 63;
    const int wave = tid >> 6;      // 0..15
    const int wA   = wave & 3;      // i-group: rows wA*32..+31
    const int wB   = wave >> 2;     // E: j-quarter; PV/output: d-quarter
    const int li   = lane & 31;
    const int h    = lane >> 5;     // k-half
    const int sl   = (li & 15) << 4;

    // XCD-grouped decode: 16 blocks sharing one (side,batch) Y-stream per XCD.
    const int bx   = blockIdx.x;
    const int xcd  = bx & 7;
    const int slot = bx >> 3;               // 0..31
    const int g    = xcd * 2 + (slot >> 4); // 0..15
    const int rt   = slot & 15;
    const int side = g >> 3;
    const int bb   = g & 7;

    const short* XHg = ws + (size_t)side * 2 * PLANE + ((size_t)bb * LSEQ + (size_t)rt * BM) * DIM;
    const short* YHg = ws + (size_t)(side ^ 1) * 2 * PLANE + (size_t)bb * LSEQ * DIM;
    const short* YTg = ws + (size_t)(side ^ 1) * 2 * PLANE + (size_t)PLANE + (size_t)bb * DIM * LSEQ;
    float* O = out + (size_t)side * PLANE + ((size_t)bb * LSEQ + (size_t)rt * BM) * DIM;

    // ---- X fragments -> registers (loop-invariant): row i = wA*32+li ----
    v8h xv[8];
    {
        const short* xr = XHg + (size_t)(wA * 32 + li) * DIM + h * 8;
        #pragma unroll
        for (int ks = 0; ks < 8; ++ks)
            xv[ks] = *(const v8h*)(const void*)(xr + ks * 16);
    }

    float runm = -INFINITY, runs = 0.f;
    v16f o = vz16();

    // staging: each wave owns 2 Y chunks + 2 Vt chunks (1KB each) per tile
    const int ch0 = wave * 2;
    const int sr0 = ch0 * 4 + (lane >> 4);
    const int sr1 = (ch0 + 1) * 4 + (lane >> 4);
    const int sc0 = ((lane & 15) * 16) ^ ((sr0 & 15) << 4);
    const int sc1 = ((lane & 15) * 16) ^ ((sr1 & 15) << 4);

    auto STAGE_Y = [&](int jt) {
        gload16((const char*)YHg + ((size_t)(jt * BJ + sr0)) * 256 + sc0,
                pool + ch0 * 1024);
        gload16((const char*)YHg + ((size_t)(jt * BJ + sr1)) * 256 + sc1,
                pool + (ch0 + 1) * 1024);
    };
    auto STAGE_V = [&](int jt, int b) {
        gload16((const char*)YTg + (size_t)sr0 * (LSEQ * 2) + (size_t)jt * (BJ * 2) + sc0,
                pool + 32768 + b * 32768 + ch0 * 1024);
        gload16((const char*)YTg + (size_t)sr1 * (LSEQ * 2) + (size_t)jt * (BJ * 2) + sc1,
                pool + 32768 + b * 32768 + (ch0 + 1) * 1024);
    };

    STAGE_Y(0);
    STAGE_V(0, 0);
    asm volatile("s_waitcnt vmcnt(0)" ::: "memory");
    __syncthreads();

    const int yrow = wB * 32 + li;      // E: A-operand row (j)
    const int prow = wA * 32 + li;      // Pt row (i)
    const int vrow = wB * 32 + li;      // PV: B-operand row (d)
    char* PtB = pool + 98304;

    for (int jt = 0; jt < NJT; ++jt) {
        const int cur = jt & 1;

        // ---- E: e[j16regs][i=li] = Y(j=wB quarter) . X^T, K=128 ----
        v16f e = vz16();
        __builtin_amdgcn_s_setprio(1);
        #pragma unroll
        for (int ks = 0; ks < 8; ++ks) {
            v8h ya = *(const v8h*)(pool + yrow * 256 + ((ks * 32 + h * 16) ^ sl));
            e = __builtin_amdgcn_mfma_f32_32x32x16_f16(ya, xv[ks], e, 0, 0, 0);
        }
        __builtin_amdgcn_s_setprio(0);

        // ---- per-row tile-max partial (row i = li; fold halves) ----
        float a0 = fmaxf(fmaxf(e[0], e[1]),  fmaxf(e[2], e[3]));
        float a1 = fmaxf(fmaxf(e[4], e[5]),  fmaxf(e[6], e[7]));
        float a2 = fmaxf(fmaxf(e[8], e[9]),  fmaxf(e[10], e[11]));
        float a3 = fmaxf(fmaxf(e[12], e[13]), fmaxf(e[14], e[15]));
        float mt = fmaxf(fmaxf(a0, a1), fmaxf(a2, a3));
        mt = fmaxf(mt, __shfl_xor(mt, 32));
        if (lane < 32) maxp[wA][wB][lane] = mt;

        asm volatile("s_waitcnt lgkmcnt(0)" ::: "memory");
        __builtin_amdgcn_s_barrier();       // B1: Y reads + maxp done
        __builtin_amdgcn_sched_barrier(0);

        // ---- issue next tile's stages (fly under softmax + PV) ----
        if (jt + 1 < NJT) {
            STAGE_Y(jt + 1);
            STAGE_V(jt + 1, cur ^ 1);
        }

        // ---- combine tile max across 4 j-quarters; defer-max update ----
        float m4 = fmaxf(fmaxf(maxp[wA][0][li], maxp[wA][1][li]),
                         fmaxf(maxp[wA][2][li], maxp[wA][3][li]));
        float f = 1.0f;
        if (m4 > runm + THR_DEFER) { f = __expf(runm - m4); runs *= f; runm = m4; }

        // ---- P = exp(E - m); own-quarter sum ----
        float s = 0.f;
        #pragma unroll
        for (int r = 0; r < 16; ++r) { e[r] = __expf(e[r] - runm); s += e[r]; }
        s += __shfl_xor(s, 32);
        runs += s;

        // ---- acc rescale (rare): f per i-row via shfl ----
        if (__any(f != 1.0f)) {
            #pragma unroll
            for (int r = 0; r < 16; ++r)
                o[r] *= __shfl(f, (r & 3) + 8 * (r >> 2) + 4 * h);
        }

        // ---- pack P -> Pt[i=prow][j = wB*32 + jb..], swizzled b64 writes ----
        #pragma unroll
        for (int gq = 0; gq < 4; ++gq) {
            unsigned u0 = pk2u(e[gq * 4 + 0], e[gq * 4 + 1]);
            unsigned u1 = pk2u(e[gq * 4 + 2], e[gq * 4 + 3]);
            unsigned long long uu = (unsigned long long)u0 | ((unsigned long long)u1 << 32);
            const int gran = (wB * 4 + gq) ^ (li & 15);
            *(unsigned long long*)(PtB + prow * 256 + gran * 16 + h * 8) = uu;
        }

        asm volatile("s_waitcnt lgkmcnt(0)" ::: "memory");
        __builtin_amdgcn_s_barrier();       // B2: Pt ready
        __builtin_amdgcn_sched_barrier(0);

        // ---- PV: o[i=regs][d=li] += P[i][j128] . Vt[d][j128] ----
        const char* Vc = pool + 32768 + cur * 32768;
        __builtin_amdgcn_s_setprio(1);
        #pragma unroll
        for (int ks = 0; ks < 8; ++ks) {
            v8h pa = *(const v8h*)(PtB + prow * 256 + (((ks * 2 + h) ^ (li & 15)) << 4));
            v8h vb = *(const v8h*)(Vc + vrow * 256 + ((ks * 32 + h * 16) ^ sl));
            o = __builtin_amdgcn_mfma_f32_32x32x16_f16(pa, vb, o, 0, 0, 0);
        }
        __builtin_amdgcn_s_setprio(0);

        asm volatile("s_waitcnt vmcnt(0) lgkmcnt(0)" ::: "memory");
        __builtin_amdgcn_s_barrier();       // B3: stages landed, Pt/Vt reads done
        __builtin_amdgcn_sched_barrier(0);
    }

    // ---- finalize: sum the 4 j-quarter denominators; write out ----
    if (lane < 32) sEx[wA][wB][lane] = runs;
    __syncthreads();
    const float inv = 1.0f / ((sEx[wA][0][li] + sEx[wA][1][li]) +
                              (sEx[wA][2][li] + sEx[wA][3][li]));
    #pragma unroll
    for (int r = 0; r < 16; ++r) {
        const int i = (r & 3) + 8 * (r >> 2) + 4 * h;
        const float fr = __shfl(inv, i);
        O[(size_t)(wA * 32 + i) * DIM + wB * 32 + li] = o[r] * fr;
    }
}

extern "C" void kernel_launch(void* const* d_in, const int* in_sizes, int n_in,
                              void* d_out, int out_size, void* d_ws, size_t ws_size,
                              hipStream_t stream) {
    const float* s1 = (const float*)d_in[0];
    const float* s2 = (const float*)d_in[1];
    float* out = (float*)d_out;
    short* ws = (short*)d_ws;   // 4 * PLANE * 2B = 16 MiB
    prepass_kernel<<<dim3(LSEQ / 64, NBATCH, 2), 256, 0, stream>>>(s1, s2, ws);
    xattn_main<<<dim3(256), 1024, 0, stream>>>(ws, out);
}